// Round 14
// baseline (266.867 us; speedup 1.0000x reference)
//
#include <hip/hip_runtime.h>

// Problem constants (B=2, L=16, D=4, K=2, N_IN=8, N_OUT=8, NC=3)
#define NSITES (1 << 17)         // 131072 sites (2*16^4)
// W:     site-stride 72 floats (18 float4), base 288 B
// U_PT:  site-stride 180 floats
// omega: flat [i][j][mu][ik] (1280 floats)
// out:   site-stride 72 floats
//
// R14: 16 threads/site = (q = output-i-pair, mu), MIX-FIRST (R4 identity:
//   V_i = sum_j omega[i,j] W_j, then acc_i += U V_i U^T -- j-sum
//   reassociated before the sandwich, verified in R4).
//   - Mix is thread-local: ZERO per-ik shuffles (R6-R13 exchanged M via
//     shfl). Lanes differing only in q read IDENTICAL W addresses ->
//     hardware merges (no extra cache lines; R13 falsified request-rate
//     sensitivity anyway).
//   - acc[2][9]+V[2][9]+U[9] -> natural VGPR ~58: UNDER the 64 cliff.
//   - LDS = omega 1312 + U-slice 16x184 = 4256 floats = 17.0 KB <= 20KB.
//   With both under the 8-wave limits, __launch_bounds__(256,8) is
//   FEASIBLE (R12's failure: LDS 28.8KB capped occupancy at 5 waves/EU,
//   so LLVM ignored the VGPR request) -> 8 waves/SIMD, 2x residency.

#define OM_OFF 0                 // [mu][ik][j][i]: mu-stride 328 (pad 320)
#define U_OFF  1312              // [site][184] (pad 180)
#define LDS_FLOATS (U_OFF + 16 * 184)   // 4256 floats = 17024 B

// V-mix for channel J: V{0,1}[e] (op)= omega[2q+{0,1}, J] * w[e]
#define MIX_CH(FIRST, J, w0,w1,w2,w3,w4,w5,w6,w7,w8) do {                    \
    const float2 o2 = *reinterpret_cast<const float2*>(                      \
                          omt + ik * 64 + (J) * 8);                          \
    const float wv[9] = {w0,w1,w2,w3,w4,w5,w6,w7,w8};                        \
    _Pragma("unroll")                                                        \
    for (int e = 0; e < 9; ++e) {                                            \
        if (FIRST) { V0[e] = o2.x * wv[e];                                   \
                     V1[e] = o2.y * wv[e]; }                                 \
        else       { V0[e] = fmaf(o2.x, wv[e], V0[e]);                       \
                     V1[e] = fmaf(o2.y, wv[e], V1[e]); }                     \
    }                                                                        \
} while (0)

// acc += U * V * U^T (fold final add into fma chain)
#define SAND(Vv, av) do {                                                    \
    _Pragma("unroll")                                                        \
    for (int a = 0; a < 3; ++a) {                                            \
        const float uw0 = fmaf(U[a*3+0], Vv[0],                              \
                          fmaf(U[a*3+1], Vv[3], U[a*3+2] * Vv[6]));          \
        const float uw1 = fmaf(U[a*3+0], Vv[1],                              \
                          fmaf(U[a*3+1], Vv[4], U[a*3+2] * Vv[7]));          \
        const float uw2 = fmaf(U[a*3+0], Vv[2],                              \
                          fmaf(U[a*3+1], Vv[5], U[a*3+2] * Vv[8]));          \
        _Pragma("unroll")                                                    \
        for (int b = 0; b < 3; ++b)                                          \
            av[a*3+b] = fmaf(uw0, U[b*3+0],                                  \
                        fmaf(uw1, U[b*3+1],                                  \
                        fmaf(uw2, U[b*3+2], av[a*3+b])));                    \
    }                                                                        \
} while (0)

__global__ __launch_bounds__(256, 8) void lconv_kernel(
    const float* __restrict__ W, const float* __restrict__ U_PT,
    const float* __restrict__ omega, float* __restrict__ out)
{
    __shared__ float lds[LDS_FLOATS];
    const int tid = threadIdx.x;

    // XCD-aware bijective swizzle: 8192 blocks, 8 XCDs, 1024-block chunks.
    const int bid = ((int)blockIdx.x & 7) * ((int)gridDim.x >> 3)
                  + ((int)blockIdx.x >> 3);
    const int s0  = bid * 16;            // 16 sites per block

    // ---- one-time staging ----
    {
        // omega -> [mu][ik][j][i] (i-stride 1, j-stride 8, ik-stride 64)
        for (int t = tid; t < 1280; t += 256) {
            const int i  = t / 160;
            const int r  = t - i * 160;
            const int j  = r / 20;
            const int r2 = r - j * 20;
            const int m  = r2 / 5;
            const int ikk = r2 - m * 5;
            lds[OM_OFF + m * 328 + ikk * 64 + j * 8 + i] = omega[t];
        }
        // U slice: 16 sites x 45 float4 -> [site][184] (lane-linear)
        const int site = tid >> 4;       // 0..15
        const int r16  = tid & 15;       // 0..15
        const float4* __restrict__ U4 =
            reinterpret_cast<const float4*>(U_PT) + (size_t)s0 * 45;
#pragma unroll
        for (int st = 0; st < 3; ++st) {
            const int f4r = st * 16 + r16;
            if (st < 2 || f4r < 45) {
                *reinterpret_cast<float4*>(
                    lds + U_OFF + site * 184 + f4r * 4) =
                    U4[site * 45 + f4r];
            }
        }
    }
    __syncthreads();

    const int local = tid >> 4;          // site local id 0..15
    const int s     = s0 + local;
    const int q     = (tid >> 2) & 3;    // output-i pair: i = 2q, 2q+1
    const int mu    = tid & 3;           // axis
    const int sh    = 12 - 4 * mu;       // bit position of x_mu in s
    const int x     = (s >> sh) & 15;

    const float* __restrict__ Ul  = lds + U_OFF + local * 184 + mu * 45;
    const float* __restrict__ omt = lds + OM_OFF + mu * 328 + q * 2;

    float acc0[9], acc1[9];
#pragma unroll
    for (int e = 0; e < 9; ++e) { acc0[e] = 0.0f; acc1[e] = 0.0f; }

#pragma unroll 1
    for (int ik = 0; ik < 5; ++ik) {
        const int k = ik - 2;

        // neighbor site along mu (uniform, branch-free)
        const int ns = s + ((((x + k + 16) & 15) - x) << sh);
        const float4* __restrict__ Wp =
            reinterpret_cast<const float4*>(W + (size_t)ns * 72);

        // ---- mix: V_i = sum_j omega[i,j,mu,ik] * W_j  (18 f4 JIT stream)
        float V0[9], V1[9];
        {
            const float4 a0 = Wp[0], a1 = Wp[1], a2 = Wp[2];
            MIX_CH(1, 0, a0.x,a0.y,a0.z,a0.w, a1.x,a1.y,a1.z,a1.w, a2.x);
            const float4 a3 = Wp[3], a4 = Wp[4];
            MIX_CH(0, 1, a2.y,a2.z,a2.w, a3.x,a3.y,a3.z,a3.w, a4.x,a4.y);
            const float4 a5 = Wp[5], a6 = Wp[6];
            MIX_CH(0, 2, a4.z,a4.w, a5.x,a5.y,a5.z,a5.w, a6.x,a6.y,a6.z);
            const float4 a7 = Wp[7], a8 = Wp[8];
            MIX_CH(0, 3, a6.w, a7.x,a7.y,a7.z,a7.w, a8.x,a8.y,a8.z,a8.w);
            const float4 a9 = Wp[9], a10 = Wp[10], a11 = Wp[11];
            MIX_CH(0, 4, a9.x,a9.y,a9.z,a9.w, a10.x,a10.y,a10.z,a10.w, a11.x);
            const float4 a12 = Wp[12], a13 = Wp[13];
            MIX_CH(0, 5, a11.y,a11.z,a11.w, a12.x,a12.y,a12.z,a12.w, a13.x,a13.y);
            const float4 a14 = Wp[14], a15 = Wp[15];
            MIX_CH(0, 6, a13.z,a13.w, a14.x,a14.y,a14.z,a14.w, a15.x,a15.y,a15.z);
            const float4 a16 = Wp[16], a17 = Wp[17];
            MIX_CH(0, 7, a15.w, a16.x,a16.y,a16.z,a16.w, a17.x,a17.y,a17.z,a17.w);
        }

        // ---- U for this (site, mu, ik) from LDS (conflict-free pattern)
        float U[9];
#pragma unroll
        for (int e = 0; e < 9; ++e) U[e] = Ul[ik * 9 + e];

        // ---- sandwich-accumulate both owned output channels
        SAND(V0, acc0);
        SAND(V1, acc1);
    }

    // reduce the 4 mu-partials within each mu-quad (lane bits 0,1)
#pragma unroll
    for (int e = 0; e < 9; ++e) {
        float v0 = acc0[e];
        v0 += __shfl_xor(v0, 1);
        v0 += __shfl_xor(v0, 2);
        acc0[e] = v0;
        float v1 = acc1[e];
        v1 += __shfl_xor(v1, 1);
        v1 += __shfl_xor(v1, 2);
        acc1[e] = v1;
    }

    // mu==0 lanes (4 per site) store their i-pair: 18 floats = 9 float2
    if (mu == 0) {
        float2* __restrict__ o2 =
            reinterpret_cast<float2*>(out + (size_t)s * 72 + q * 18);
        o2[0] = make_float2(acc0[0], acc0[1]);
        o2[1] = make_float2(acc0[2], acc0[3]);
        o2[2] = make_float2(acc0[4], acc0[5]);
        o2[3] = make_float2(acc0[6], acc0[7]);
        o2[4] = make_float2(acc0[8], acc1[0]);
        o2[5] = make_float2(acc1[1], acc1[2]);
        o2[6] = make_float2(acc1[3], acc1[4]);
        o2[7] = make_float2(acc1[5], acc1[6]);
        o2[8] = make_float2(acc1[7], acc1[8]);
    }
}

extern "C" void kernel_launch(void* const* d_in, const int* in_sizes, int n_in,
                              void* d_out, int out_size, void* d_ws, size_t ws_size,
                              hipStream_t stream) {
    const float* W   = (const float*)d_in[0];
    const float* U   = (const float*)d_in[1];
    const float* om  = (const float*)d_in[2];
    float*       out = (float*)d_out;

    const int block = 256;
    const int grid  = NSITES / 16;    // 8192 blocks, 16 sites each
    hipLaunchKernelGGL(lconv_kernel, dim3(grid), dim3(block), 0, stream,
                       W, U, om, out);
}